// Round 1
// baseline (692.671 us; speedup 1.0000x reference)
//
#include <hip/hip_runtime.h>

#define SIZE_N 1024
#define DDIM   65536
#define D_TILE 64
#define S_CHUNK 64
#define NCHUNK (SIZE_N / S_CHUNK)   // 16
#define PITCH  65                   // 64 + 1 pad -> <=2-way LDS bank aliasing (free)

// tile[s_local * PITCH + d_local], 64x65 floats = 16.6 KB
__global__ __launch_bounds__(256, 4) void reghd_main(
    const float* __restrict__ x,
    const float* __restrict__ w,
    const float* __restrict__ bias,
    const float* __restrict__ alpha,
    const float* __restrict__ M,
    float* __restrict__ out)
{
    __shared__ float tile[S_CHUNK * PITCH];

    const int t      = threadIdx.x;
    const int lane16 = t & 15;          // s-quad index within row group
    const int grp    = t >> 4;          // 0..15 row group
    const int d0     = blockIdx.x * D_TILE;

    float* __restrict__ hvs = out + 1 + DDIM;   // hvs[s*DDIM + d]

    float acc[4] = {0.f, 0.f, 0.f, 0.f};        // row sums for rows grp+16p

    for (int c = 0; c < NCHUNK; ++c) {
        const int s0 = c * S_CHUNK;
        const int sx = lane16 * 4;

        // x/alpha quads: 16B aligned (s0+sx multiple of 4), L1-resident after first chunk
        const float4 x4 = *reinterpret_cast<const float4*>(x + s0 + sx);
        const float4 a4 = *reinterpret_cast<const float4*>(alpha + s0 + sx);

        #pragma unroll
        for (int p = 0; p < 4; ++p) {
            const int row = grp + 16 * p;               // 0..63
            const size_t base = (size_t)(d0 + row) * SIZE_N + s0 + sx;
            const float4 w4 = *reinterpret_cast<const float4*>(w + base);
            const float4 b4 = *reinterpret_cast<const float4*>(bias + base);

            const float p0 = x4.x * w4.x;
            const float p1 = x4.y * w4.y;
            const float p2 = x4.z * w4.z;
            const float p3 = x4.w * w4.w;
            const float e0 = cosf(p0 + b4.x) * sinf(p0);
            const float e1 = cosf(p1 + b4.y) * sinf(p1);
            const float e2 = cosf(p2 + b4.z) * sinf(p2);
            const float e3 = cosf(p3 + b4.w) * sinf(p3);

            // transpose into LDS: tile[s][d]
            tile[(sx + 0) * PITCH + row] = e0;
            tile[(sx + 1) * PITCH + row] = e1;
            tile[(sx + 2) * PITCH + row] = e2;
            tile[(sx + 3) * PITCH + row] = e3;

            acc[p] += e0 * a4.x + e1 * a4.y + e2 * a4.z + e3 * a4.w;
        }
        __syncthreads();

        // Phase B: coalesced transposed write. Each wave instr: 64 consecutive d
        // (256 B contiguous). hvs dword offset is 1 mod 4 -> scalar stores only.
        #pragma unroll
        for (int p2 = 0; p2 < 16; ++p2) {
            const int idx  = t + 256 * p2;
            const int srow = idx >> 6;      // uniform per wave
            const int dl   = idx & 63;      // = lane
            const float v  = tile[srow * PITCH + dl];
            hvs[(size_t)(s0 + srow) * DDIM + d0 + dl] = v;
        }
        __syncthreads();
    }

    // bundled -> q, and partial model_result = dot(q, M) for this tile
    float local_dot = 0.f;
    #pragma unroll
    for (int p = 0; p < 4; ++p) {
        float s = acc[p];
        #pragma unroll
        for (int m = 1; m < 16; m <<= 1) s += __shfl_xor(s, m);
        if (lane16 == 0) {
            const int d = d0 + grp + 16 * p;
            const float qv = (s > 0.f) ? 1.f : -1.f;
            out[1 + d] = qv;
            local_dot += qv * M[d];
        }
    }
    // lanes 0,16,32,48 hold partials; fold to lane 0, one atomic per wave
    local_dot += __shfl_xor(local_dot, 16);
    local_dot += __shfl_xor(local_dot, 32);
    if ((t & 63) == 0) atomicAdd(out, local_dot);
}

extern "C" void kernel_launch(void* const* d_in, const int* in_sizes, int n_in,
                              void* d_out, int out_size, void* d_ws, size_t ws_size,
                              hipStream_t stream) {
    const float* x     = (const float*)d_in[0];
    const float* w     = (const float*)d_in[1];
    const float* bias  = (const float*)d_in[2];
    const float* alpha = (const float*)d_in[3];
    const float* M     = (const float*)d_in[4];
    float* out = (float*)d_out;

    // out[0] accumulates model_result via atomics; harness poisons d_out each call
    hipMemsetAsync(out, 0, sizeof(float), stream);

    reghd_main<<<dim3(DDIM / D_TILE), dim3(256), 0, stream>>>(x, w, bias, alpha, M, out);
}